// Round 3
// baseline (298.606 us; speedup 1.0000x reference)
//
#include <hip/hip_runtime.h>

typedef __attribute__((ext_vector_type(8))) short short8;
typedef __attribute__((ext_vector_type(4))) float floatx4;

__device__ __forceinline__ float bf2f(unsigned short b) {
    union { unsigned int u; float f; } v; v.u = ((unsigned int)b) << 16; return v.f;
}
__device__ __forceinline__ unsigned short f2bf(float f) {
    union { float f; unsigned int u; } v; v.f = f;
    unsigned int r = v.u + 0x7fffu + ((v.u >> 16) & 1u);   // round-to-nearest-even
    return (unsigned short)(r >> 16);
}

// load 16 contiguous f32 (16B-aligned), convert to bf16
union Pack16 { uint4 v[2]; unsigned short u[16]; };
__device__ __forceinline__ void load16_f32_bf(const float* __restrict__ src, Pack16& t) {
    float tmp[16];
    *(float4*)&tmp[0]  = ((const float4*)src)[0];
    *(float4*)&tmp[4]  = ((const float4*)src)[1];
    *(float4*)&tmp[8]  = ((const float4*)src)[2];
    *(float4*)&tmp[12] = ((const float4*)src)[3];
#pragma unroll
    for (int i = 0; i < 16; i++) t.u[i] = f2bf(tmp[i]);
}

#define MFMA16(a, b, c) __builtin_amdgcn_mfma_f32_16x16x32_bf16((a), (b), (c), 0, 0, 0)

// ---------------------------------------------------------------------------
// GEMM: C[M,N] = A[M,K] @ B[K,N], f32 accumulate, bf16 MFMA compute.
// A is f32 (input x) or bf16 (my intermediate); B always f32 (weights);
// C is bf16 (intermediate) or f32 (final output).
// 64x64 tile, BK=64. 4 waves, each a 32x32 quadrant of 2x2 16x16x32 MFMAs.
// B staged transposed ([n][k]) so all fragment reads are ds_read_b128.
// ---------------------------------------------------------------------------
template<bool A_F32, bool C_F32>
__global__ __launch_bounds__(256) void gemm64(
    const void* __restrict__ Ap, const float* __restrict__ B,
    void* __restrict__ Cp, int M, int N, int K)
{
    __shared__ __align__(16) unsigned short As[64][72];   // [m][k]
    __shared__ __align__(16) unsigned short Bs[64][72];   // [n][k]  (transposed)
    const int tid  = threadIdx.x;
    const int m0   = blockIdx.y * 64, n0 = blockIdx.x * 64;
    const int wv   = tid >> 6, lane = tid & 63;
    const int quad = lane >> 4, l15 = lane & 15;
    const int wm   = (wv >> 1) * 32, wn = (wv & 1) * 32;

    const int am = tid >> 2, ac = (tid & 3) * 16;   // A stage: row, col-chunk
    const int bk = tid >> 2, bn = (tid & 3) * 16;   // B stage: k-row, n-chunk

    floatx4 acc[2][2] = {};

    for (int k0 = 0; k0 < K; k0 += 64) {
        __syncthreads();
        // stage A
        if (A_F32) {
            Pack16 t;
            load16_f32_bf((const float*)Ap + (size_t)(m0 + am) * K + k0 + ac, t);
            *(uint4*)&As[am][ac]     = t.v[0];
            *(uint4*)&As[am][ac + 8] = t.v[1];
        } else {
            const uint4* ag = (const uint4*)((const unsigned short*)Ap +
                                             (size_t)(m0 + am) * K + k0 + ac);
            uint4 a0v = ag[0], a1v = ag[1];
            *(uint4*)&As[am][ac]     = a0v;
            *(uint4*)&As[am][ac + 8] = a1v;
        }
        // stage B transposed (f32 -> bf16)
        {
            Pack16 t;
            load16_f32_bf(B + (size_t)(k0 + bk) * N + n0 + bn, t);
#pragma unroll
            for (int j = 0; j < 16; j++) Bs[bn + j][bk] = t.u[j];
        }
        __syncthreads();

#pragma unroll
        for (int ks = 0; ks < 2; ks++) {
            const int kc = ks * 32 + quad * 8;
            short8 a_0 = *(const short8*)&As[wm + l15][kc];
            short8 a_1 = *(const short8*)&As[wm + 16 + l15][kc];
            short8 b_0 = *(const short8*)&Bs[wn + l15][kc];
            short8 b_1 = *(const short8*)&Bs[wn + 16 + l15][kc];
            acc[0][0] = MFMA16(a_0, b_0, acc[0][0]);
            acc[0][1] = MFMA16(a_0, b_1, acc[0][1]);
            acc[1][0] = MFMA16(a_1, b_0, acc[1][0]);
            acc[1][1] = MFMA16(a_1, b_1, acc[1][1]);
        }
    }

#pragma unroll
    for (int mt = 0; mt < 2; mt++)
#pragma unroll
        for (int nt = 0; nt < 2; nt++)
#pragma unroll
            for (int r = 0; r < 4; r++) {
                const int row = m0 + wm + mt * 16 + quad * 4 + r;
                const int col = n0 + wn + nt * 16 + l15;
                if (C_F32)
                    ((float*)Cp)[(size_t)row * N + col] = acc[mt][nt][r];
                else
                    ((unsigned short*)Cp)[(size_t)row * N + col] = f2bf(acc[mt][nt][r]);
            }
}

// ---------------------------------------------------------------------------
// Depthwise conv k=3 same-pad along w, and re-layout [w][c] -> head-major
// [h][w][d] (c = h*64+d). Same conv weights for q,k,v (reference quirk).
// in/out are bf16 intermediates; cw is the f32 input (BINS,1,3).
// ---------------------------------------------------------------------------
__global__ __launch_bounds__(256) void conv_heads(
    const unsigned short* __restrict__ in, const float* __restrict__ cw,
    unsigned short* __restrict__ out)
{
    const int idx = blockIdx.x * 256 + threadIdx.x;   // [0, 2048*1024)
    const int w = idx >> 10, c = idx & 1023;
    const float c0 = cw[c * 3 + 0];
    const float c1 = cw[c * 3 + 1];
    const float c2 = cw[c * 3 + 2];
    float acc = bf2f(in[(size_t)w * 1024 + c]) * c1;
    if (w > 0)    acc += bf2f(in[(size_t)(w - 1) * 1024 + c]) * c0;
    if (w < 2047) acc += bf2f(in[(size_t)(w + 1) * 1024 + c]) * c2;
    out[((size_t)(c >> 6) * 2048 + w) * 64 + (c & 63)] = f2bf(acc);
}

// ---------------------------------------------------------------------------
// Fused attention per (q-tile of 64, head). Augmented features:
//   Q'[i] = [q_i | er[:, i]]  (128)     K'[j] = [k_j | q_j]  (128)
//   S[i,j] = (Q'.K')/32  ->  online softmax  ->  O += P @ V
// 4 waves, wave w owns Q rows [w*16, w*16+16). P goes through LDS for the
// C-layout -> A-layout transform. er is the f32 input (64, 2048).
// ---------------------------------------------------------------------------
__global__ __launch_bounds__(256) void attn16(
    const unsigned short* __restrict__ qh, const unsigned short* __restrict__ kh,
    const unsigned short* __restrict__ vh, const float* __restrict__ er,
    unsigned short* __restrict__ outp)
{
    __shared__ __align__(16) unsigned short Qp[64][136];  // [i][0:64)=q, [64:128)=er^T
    __shared__ __align__(16) unsigned short Kp[64][136];  // [j][0:64)=k, [64:128)=q
    __shared__ __align__(16) unsigned short Vt[64][72];   // [dd][j]  (transposed)
    __shared__ __align__(16) unsigned short Ps[64][72];   // [i][j] bf16 P round-trip

    const int tid  = threadIdx.x;
    const int qb   = blockIdx.x, h = blockIdx.y;
    const int q0   = qb * 64;
    const size_t hoff = (size_t)h * 2048 * 64;
    const unsigned short* qb_ = qh + hoff;
    const unsigned short* kb_ = kh + hoff;
    const unsigned short* vb_ = vh + hoff;
    const int wv = tid >> 6, lane = tid & 63;
    const int quad = lane >> 4, l15 = lane & 15;

    // ---- stage Q' (once per block) ----
    {
        const int m = tid >> 2, kc = (tid & 3) * 16;
        const uint4* g = (const uint4*)(qb_ + (size_t)(q0 + m) * 64 + kc);
        *(uint4*)&Qp[m][kc]     = g[0];
        *(uint4*)&Qp[m][kc + 8] = g[1];
        // er part: Qp[i][64+dd] = er[dd][q0+i];  m plays dd, kc plays i-chunk
        Pack16 t;
        load16_f32_bf(er + (size_t)m * 2048 + q0 + kc, t);
#pragma unroll
        for (int j = 0; j < 16; j++) Qp[kc + j][64 + m] = t.u[j];
    }

    floatx4 oacc[4] = {};
    float m_run[4], l_run[4];
#pragma unroll
    for (int r = 0; r < 4; r++) { m_run[r] = -1e30f; l_run[r] = 0.f; }

    for (int kt = 0; kt < 32; kt++) {
        __syncthreads();   // guards Kp/Vt reuse (and Qp staging on iter 0)
        // ---- stage K' and V^T for this key tile ----
        {
            const int j = tid >> 2, sg = tid & 3;
            const unsigned short* src =
                ((sg < 2) ? kb_ : qb_) + (size_t)(kt * 64 + j) * 64 + (sg & 1) * 32;
            const uint4* g = (const uint4*)src;
            uint4 x0 = g[0], x1 = g[1], x2 = g[2], x3 = g[3];
            uint4* dst = (uint4*)&Kp[j][sg * 32];
            dst[0] = x0; dst[1] = x1; dst[2] = x2; dst[3] = x3;

            const int dd0 = (tid & 3) * 16;
            union { uint4 v[2]; unsigned short u[16]; } vu;
            const uint4* gv = (const uint4*)(vb_ + (size_t)(kt * 64 + j) * 64 + dd0);
            vu.v[0] = gv[0]; vu.v[1] = gv[1];
#pragma unroll
            for (int x = 0; x < 16; x++) Vt[dd0 + x][j] = vu.u[x];
        }
        __syncthreads();

        // ---- S tile: Q'[16 x 128] . K'^T[128 x 64] ----
        floatx4 s[4] = {};
#pragma unroll
        for (int ks = 0; ks < 4; ks++) {
            const int kc = ks * 32 + quad * 8;
            short8 af = *(const short8*)&Qp[wv * 16 + l15][kc];
#pragma unroll
            for (int jt = 0; jt < 4; jt++) {
                short8 bf = *(const short8*)&Kp[jt * 16 + l15][kc];
                s[jt] = MFMA16(af, bf, s[jt]);
            }
        }

        // ---- online softmax update (rows = quad*4+r, cols across 16 lanes) --
        const float sc = 0.03125f;   // 1/sqrt(1024)
        float alpha[4];
#pragma unroll
        for (int r = 0; r < 4; r++) {
            float mx = fmaxf(fmaxf(s[0][r], s[1][r]), fmaxf(s[2][r], s[3][r])) * sc;
#pragma unroll
            for (int off = 1; off < 16; off <<= 1) mx = fmaxf(mx, __shfl_xor(mx, off));
            const float mnew = fmaxf(m_run[r], mx);
            alpha[r] = __expf(m_run[r] - mnew);
            float rsum = 0.f;
#pragma unroll
            for (int jt = 0; jt < 4; jt++) {
                float p = __expf(s[jt][r] * sc - mnew);
                s[jt][r] = p; rsum += p;
            }
#pragma unroll
            for (int off = 1; off < 16; off <<= 1) rsum += __shfl_xor(rsum, off);
            l_run[r] = l_run[r] * alpha[r] + rsum;
            m_run[r] = mnew;
        }

        // ---- write P (C-layout) to LDS, rescale O ----
#pragma unroll
        for (int jt = 0; jt < 4; jt++)
#pragma unroll
            for (int r = 0; r < 4; r++)
                Ps[wv * 16 + quad * 4 + r][jt * 16 + l15] = f2bf(s[jt][r]);
#pragma unroll
        for (int nt = 0; nt < 4; nt++)
#pragma unroll
            for (int r = 0; r < 4; r++) oacc[nt][r] *= alpha[r];
        __syncthreads();

        // ---- O += P[16 x 64] . V[64 x 64] ----
#pragma unroll
        for (int ks = 0; ks < 2; ks++) {
            const int kc = ks * 32 + quad * 8;
            short8 af = *(const short8*)&Ps[wv * 16 + l15][kc];
#pragma unroll
            for (int nt = 0; nt < 4; nt++) {
                short8 bf = *(const short8*)&Vt[nt * 16 + l15][kc];
                oacc[nt] = MFMA16(af, bf, oacc[nt]);
            }
        }
    }

    // ---- epilogue: O/l -> [w][c] layout (bf16) for the output GEMM ----
#pragma unroll
    for (int r = 0; r < 4; r++) {
        const float inv = 1.0f / l_run[r];
        const int row = q0 + wv * 16 + quad * 4 + r;
#pragma unroll
        for (int nt = 0; nt < 4; nt++) {
            const int col = h * 64 + nt * 16 + l15;
            outp[(size_t)row * 1024 + col] = f2bf(oacc[nt][r] * inv);
        }
    }
}

// ---------------------------------------------------------------------------
extern "C" void kernel_launch(void* const* d_in, const int* in_sizes, int n_in,
                              void* d_out, int out_size, void* d_ws, size_t ws_size,
                              hipStream_t stream)
{
    // Reference dtypes are float32 for ALL inputs and the output.
    const float* x  = (const float*)d_in[0];
    const float* wq = (const float*)d_in[1];
    const float* wk = (const float*)d_in[2];
    const float* wv = (const float*)d_in[3];
    const float* wo = (const float*)d_in[4];
    const float* cw = (const float*)d_in[5];
    const float* er = (const float*)d_in[6];
    float* out = (float*)d_out;
    unsigned short* ws = (unsigned short*)d_ws;   // bf16 intermediates

    // 4-buffer ping-pong: total ws use = 4 * 2048*1024 * 2B = 16 MiB.
    const size_t SZ = (size_t)2048 * 1024;
    unsigned short* b0 = ws;            // q_raw -> kh
    unsigned short* b1 = ws + SZ;       // k_raw -> vh
    unsigned short* b2 = ws + 2 * SZ;   // v_raw -> attn_out
    unsigned short* b3 = ws + 3 * SZ;   // qh

    dim3 gg(1024 / 64, 2048 / 64);
    gemm64<true,  false><<<gg, 256, 0, stream>>>(x, wq, b0, 2048, 1024, 1024); // q_raw
    gemm64<true,  false><<<gg, 256, 0, stream>>>(x, wk, b1, 2048, 1024, 1024); // k_raw
    gemm64<true,  false><<<gg, 256, 0, stream>>>(x, wv, b2, 2048, 1024, 1024); // v_raw
    conv_heads<<<8192, 256, 0, stream>>>(b0, cw, b3);              // qh = conv(q_raw)
    conv_heads<<<8192, 256, 0, stream>>>(b1, cw, b0);              // kh = conv(k_raw)
    conv_heads<<<8192, 256, 0, stream>>>(b2, cw, b1);              // vh = conv(v_raw)
    attn16<<<dim3(32, 16), 256, 0, stream>>>(b3, b0, b1, er, b2);  // attn -> b2
    gemm64<false, true><<<gg, 256, 0, stream>>>(b2, wo, out, 2048, 1024, 1024);
}

// Round 4
// 227.070 us; speedup vs baseline: 1.3150x; 1.3150x over previous
//
#include <hip/hip_runtime.h>

typedef __attribute__((ext_vector_type(8))) short short8;
typedef __attribute__((ext_vector_type(4))) float floatx4;

__device__ __forceinline__ float bf2f(unsigned short b) {
    union { unsigned int u; float f; } v; v.u = ((unsigned int)b) << 16; return v.f;
}
__device__ __forceinline__ unsigned short f2bf(float f) {
    union { float f; unsigned int u; } v; v.f = f;
    unsigned int r = v.u + 0x7fffu + ((v.u >> 16) & 1u);   // RNE
    return (unsigned short)(r >> 16);
}

union Pack16 { uint4 v[2]; unsigned short u[16]; };
// load 16 contiguous f32, scale, convert to bf16
__device__ __forceinline__ void cvt16(const float* __restrict__ src, float s, Pack16& t) {
    float tmp[16];
    *(float4*)&tmp[0]  = ((const float4*)src)[0];
    *(float4*)&tmp[4]  = ((const float4*)src)[1];
    *(float4*)&tmp[8]  = ((const float4*)src)[2];
    *(float4*)&tmp[12] = ((const float4*)src)[3];
#pragma unroll
    for (int i = 0; i < 16; i++) t.u[i] = f2bf(tmp[i] * s);
}

#define MFMA16(a, b, c) __builtin_amdgcn_mfma_f32_16x16x32_bf16((a), (b), (c), 0, 0, 0)

// ---------------------------------------------------------------------------
// 128x128-tile GEMM, BK=64, 4 waves in 2x2, each wave 4x4 MFMA 16x16 tiles.
// A: f32 (x) or bf16 (attn_out), row-major [M][K].
// B: BT_PRE ? bf16 pre-transposed [N][K] : f32 row-major [K][N] (transpose-
//    staged into LDS with an XOR chunk swizzle so scatter stores are
//    conflict-free and fragment reads stay ds_read_b128).
// Fused over up to 3 (B,C) pairs: sel = blockIdx.x>>3, n0 = (blockIdx.x&7)*128.
// ---------------------------------------------------------------------------
template<bool A_F32, bool BT_PRE, bool C_F32>
__global__ __launch_bounds__(256) void gemm128(
    const void* __restrict__ Ap,
    const void* __restrict__ B0, const void* __restrict__ B1, const void* __restrict__ B2,
    void* __restrict__ C0, void* __restrict__ C1, void* __restrict__ C2,
    int M, int N, int K)
{
    __shared__ __align__(16) unsigned short As[128][72];   // [m][k]
    __shared__ __align__(16) unsigned short Bs[128][72];   // [n][k] (chunk-swizzled if !BT_PRE)
    const int tid = threadIdx.x;
    const int sel = blockIdx.x >> 3;
    const int n0  = (blockIdx.x & 7) * 128;
    const int m0  = blockIdx.y * 128;
    const void* Bp = (sel == 0) ? B0 : (sel == 1) ? B1 : B2;
    void*       Cp = (sel == 0) ? C0 : (sel == 1) ? C1 : C2;

    const int wv = tid >> 6, lane = tid & 63;
    const int quad = lane >> 4, l15 = lane & 15;
    const int wm0 = (wv >> 1) * 64, wn0 = (wv & 1) * 64;

    floatx4 acc[4][4] = {};

    for (int k0 = 0; k0 < K; k0 += 64) {
        __syncthreads();
        // ---- stage A: 128x64, two phases of 64 rows; 4 threads/row x 16 el --
        {
            const int r = tid >> 2, c = (tid & 3) * 16;
#pragma unroll
            for (int p = 0; p < 2; p++) {
                const int row = p * 64 + r;
                if (A_F32) {
                    Pack16 t;
                    cvt16((const float*)Ap + (size_t)(m0 + row) * K + k0 + c, 1.0f, t);
                    *(uint4*)&As[row][c]     = t.v[0];
                    *(uint4*)&As[row][c + 8] = t.v[1];
                } else {
                    const uint4* a = (const uint4*)((const unsigned short*)Ap +
                                                    (size_t)(m0 + row) * K + k0 + c);
                    uint4 x0 = a[0], x1 = a[1];
                    *(uint4*)&As[row][c]     = x0;
                    *(uint4*)&As[row][c + 8] = x1;
                }
            }
        }
        // ---- stage B ----
        if (BT_PRE) {
            const int r = tid >> 2, c = (tid & 3) * 16;
#pragma unroll
            for (int p = 0; p < 2; p++) {
                const int row = p * 64 + r;
                const uint4* b = (const uint4*)((const unsigned short*)Bp +
                                                (size_t)(n0 + row) * K + k0 + c);
                uint4 x0 = b[0], x1 = b[1];
                *(uint4*)&Bs[row][c]     = x0;
                *(uint4*)&Bs[row][c + 8] = x1;
            }
        } else {
            // f32 [k][n] -> Bs[n][ (k/8 ^ ((n>>5)&3))*8 + k%8 ]
            const int kr = tid >> 2, nb = (tid & 3) * 32;
            float t[32];
            const float* b = (const float*)Bp + (size_t)(k0 + kr) * N + n0 + nb;
#pragma unroll
            for (int i = 0; i < 8; i++) *(float4*)&t[i * 4] = ((const float4*)b)[i];
            const int col = ((kr >> 3) ^ ((nb >> 5) & 3)) * 8 + (kr & 7);
#pragma unroll
            for (int j = 0; j < 32; j++) Bs[nb + j][col] = f2bf(t[j]);
        }
        __syncthreads();

#pragma unroll
        for (int ks = 0; ks < 2; ks++) {
            const int kc = ks * 32 + quad * 8;
            short8 af[4], bfr[4];
#pragma unroll
            for (int i = 0; i < 4; i++)
                af[i] = *(const short8*)&As[wm0 + i * 16 + l15][kc];
#pragma unroll
            for (int i = 0; i < 4; i++) {
                int bcol;
                if (BT_PRE) bcol = kc;
                else {
                    const int cx = ((wn0 + i * 16) >> 5) & 3;
                    bcol = ((ks * 4 + quad) ^ cx) * 8;
                }
                bfr[i] = *(const short8*)&Bs[wn0 + i * 16 + l15][bcol];
            }
#pragma unroll
            for (int mt = 0; mt < 4; mt++)
#pragma unroll
                for (int nt = 0; nt < 4; nt++)
                    acc[mt][nt] = MFMA16(af[mt], bfr[nt], acc[mt][nt]);
        }
    }

#pragma unroll
    for (int mt = 0; mt < 4; mt++)
#pragma unroll
        for (int nt = 0; nt < 4; nt++)
#pragma unroll
            for (int r = 0; r < 4; r++) {
                const int row = m0 + wm0 + mt * 16 + quad * 4 + r;
                const int col = n0 + wn0 + nt * 16 + l15;
                if (C_F32)
                    ((float*)Cp)[(size_t)row * N + col] = acc[mt][nt][r];
                else
                    ((unsigned short*)Cp)[(size_t)row * N + col] = f2bf(acc[mt][nt][r]);
            }
}

// ---------------------------------------------------------------------------
// Weight transpose: W f32 [K][N] -> WT bf16 [N][K]. 64x64 LDS tiles.
// ---------------------------------------------------------------------------
__global__ __launch_bounds__(256) void wtrans(
    const float* __restrict__ W, unsigned short* __restrict__ WT, int Kd, int Nd)
{
    __shared__ __align__(16) unsigned short T[64][72];
    const int tid = threadIdx.x;
    const int n0 = blockIdx.x * 64, k0 = blockIdx.y * 64;
    {
        const int kr = tid >> 2, nc = (tid & 3) * 16;
        Pack16 t;
        cvt16(W + (size_t)(k0 + kr) * Nd + n0 + nc, 1.0f, t);
#pragma unroll
        for (int j = 0; j < 16; j++) T[nc + j][kr] = t.u[j];
    }
    __syncthreads();
    {
        const int nr = tid >> 2, kc = (tid & 3) * 16;
        uint4 x0 = *(const uint4*)&T[nr][kc];
        uint4 x1 = *(const uint4*)&T[nr][kc + 8];
        uint4* dst = (uint4*)(WT + (size_t)(n0 + nr) * Kd + k0 + kc);
        dst[0] = x0; dst[1] = x1;
    }
}

// ---------------------------------------------------------------------------
// Depthwise conv k=3 same-pad along w, layout-preserving [w][c] bf16->bf16.
// ---------------------------------------------------------------------------
__global__ __launch_bounds__(256) void conv_qk(
    const unsigned short* __restrict__ in, const float* __restrict__ cw,
    unsigned short* __restrict__ out)
{
    const int idx = blockIdx.x * 256 + threadIdx.x;   // [0, 2048*128)
    const int w = idx >> 7, c0 = (idx & 127) * 8;
    union { uint4 v; unsigned short u[8]; } a = {}, b, c = {};
    b.v = *(const uint4*)(in + (size_t)w * 1024 + c0);
    if (w > 0)    a.v = *(const uint4*)(in + (size_t)(w - 1) * 1024 + c0);
    if (w < 2047) c.v = *(const uint4*)(in + (size_t)(w + 1) * 1024 + c0);
    union { uint4 v; unsigned short u[8]; } o;
#pragma unroll
    for (int i = 0; i < 8; i++) {
        const float* k3 = cw + (size_t)(c0 + i) * 3;
        o.u[i] = f2bf(bf2f(a.u[i]) * k3[0] + bf2f(b.u[i]) * k3[1] + bf2f(c.u[i]) * k3[2]);
    }
    *(uint4*)(out + (size_t)w * 1024 + c0) = o.v;
}

// ---------------------------------------------------------------------------
// Depthwise conv + per-head transpose: v_raw [w][c] -> vT [h*64+d][w].
// Block = (wtile of 64, head). 64x64 LDS transpose tile.
// ---------------------------------------------------------------------------
__global__ __launch_bounds__(256) void conv_vt(
    const unsigned short* __restrict__ in, const float* __restrict__ cw,
    unsigned short* __restrict__ vT)
{
    __shared__ __align__(16) unsigned short T[64][72];
    const int tid = threadIdx.x;
    const int w0 = blockIdx.x * 64, h = blockIdx.y;
    {
        const int wr = tid >> 2, c4 = (tid & 3) * 16;
        const int cg = h * 64 + c4;
        const int w = w0 + wr;
        union { uint4 v[2]; unsigned short u[16]; } a = {}, b, c = {};
        b.v[0] = *(const uint4*)(in + (size_t)w * 1024 + cg);
        b.v[1] = *(const uint4*)(in + (size_t)w * 1024 + cg + 8);
        if (w > 0) {
            a.v[0] = *(const uint4*)(in + (size_t)(w - 1) * 1024 + cg);
            a.v[1] = *(const uint4*)(in + (size_t)(w - 1) * 1024 + cg + 8);
        }
        if (w < 2047) {
            c.v[0] = *(const uint4*)(in + (size_t)(w + 1) * 1024 + cg);
            c.v[1] = *(const uint4*)(in + (size_t)(w + 1) * 1024 + cg + 8);
        }
#pragma unroll
        for (int i = 0; i < 16; i++) {
            const float* k3 = cw + (size_t)(cg + i) * 3;
            T[c4 + i][wr] = f2bf(bf2f(a.u[i]) * k3[0] + bf2f(b.u[i]) * k3[1] +
                                 bf2f(c.u[i]) * k3[2]);
        }
    }
    __syncthreads();
    {
        const int dr = tid >> 2, w4 = (tid & 3) * 16;
        uint4 x0 = *(const uint4*)&T[dr][w4];
        uint4 x1 = *(const uint4*)&T[dr][w4 + 8];
        uint4* dst = (uint4*)(vT + (size_t)(h * 64 + dr) * 2048 + w0 + w4);
        dst[0] = x0; dst[1] = x1;
    }
}

// ---------------------------------------------------------------------------
// Fused attention per (q-tile 64, head). Augmented 128-dim features:
//   Q'[i] = [q_i | er[:,i]] / 32      K'[j] = [k_j | q_j]
//   S = Q'.K'  (pre-scaled)  ->  fixed-max softmax (scores are O(1); no
//   online max needed)  ->  O += P @ V ; divide by l at the end.
// q,k read straight from [w][c] conv outputs; V from pre-transposed vT.
// All kt-loop staging is contiguous uint4 copies. Ps is wave-local (no
// barrier between P-write and PV).
// ---------------------------------------------------------------------------
__global__ __launch_bounds__(256) void attn16(
    const unsigned short* __restrict__ qc, const unsigned short* __restrict__ kc,
    const unsigned short* __restrict__ vT, const float* __restrict__ er,
    unsigned short* __restrict__ outp)
{
    __shared__ __align__(16) unsigned short Qp[64][136];  // [i][0:64)=q/32, [64:128)=er^T/32
    __shared__ __align__(16) unsigned short Kp[64][136];  // [j][0:64)=k, [64:128)=q
    __shared__ __align__(16) unsigned short Vt[64][72];   // [d][j]
    __shared__ __align__(16) unsigned short Ps[64][72];   // [i][j]

    const int tid = threadIdx.x;
    const int q0 = blockIdx.x * 64, h = blockIdx.y;
    const int wv = tid >> 6, lane = tid & 63;
    const int quad = lane >> 4, l15 = lane & 15;
    const float sc = 0.03125f;   // 1/sqrt(1024)

    // ---- stage Q' (once): q part scaled, er part transposed+scaled ----
    {
        const int m = tid >> 2, c4 = (tid & 3) * 16;
        union { uint4 v[2]; unsigned short u[16]; } t;
        t.v[0] = *(const uint4*)(qc + (size_t)(q0 + m) * 1024 + h * 64 + c4);
        t.v[1] = *(const uint4*)(qc + (size_t)(q0 + m) * 1024 + h * 64 + c4 + 8);
#pragma unroll
        for (int i = 0; i < 16; i++) t.u[i] = f2bf(bf2f(t.u[i]) * sc);
        *(uint4*)&Qp[m][c4]     = t.v[0];
        *(uint4*)&Qp[m][c4 + 8] = t.v[1];
        Pack16 e;
        cvt16(er + (size_t)m * 2048 + q0 + c4, sc, e);   // m plays d (0..63)
#pragma unroll
        for (int j = 0; j < 16; j++) Qp[c4 + j][64 + m] = e.u[j];
    }

    floatx4 oacc[4] = {};
    float lp[4] = {0.f, 0.f, 0.f, 0.f};

    for (int kt = 0; kt < 32; kt++) {
        __syncthreads();   // staging writes vs prior-iter reads (iter0: Qp cover)
        {
            // K' rows: [k | q], 4 threads/row x 32 shorts
            const int j = tid >> 2, p = tid & 3;
            const unsigned short* src = ((p < 2) ? kc : qc) +
                (size_t)(kt * 64 + j) * 1024 + h * 64 + (p & 1) * 32;
            const uint4* g = (const uint4*)src;
            uint4 x0 = g[0], x1 = g[1], x2 = g[2], x3 = g[3];
            uint4* dst = (uint4*)&Kp[j][p * 32];
            dst[0] = x0; dst[1] = x1; dst[2] = x2; dst[3] = x3;
            // V tile from vT: straight copy, 4 threads/row x 16 shorts
            const int dd = tid >> 2, c4 = (tid & 3) * 16;
            const uint4* gv = (const uint4*)(vT + (size_t)(h * 64 + dd) * 2048 +
                                             kt * 64 + c4);
            uint4 y0 = gv[0], y1 = gv[1];
            *(uint4*)&Vt[dd][c4]     = y0;
            *(uint4*)&Vt[dd][c4 + 8] = y1;
        }
        __syncthreads();

        // ---- S = Q'[16x128] . K'^T[128x64] (already scaled) ----
        floatx4 s[4] = {};
#pragma unroll
        for (int ks = 0; ks < 4; ks++) {
            const int kcol = ks * 32 + quad * 8;
            short8 af = *(const short8*)&Qp[wv * 16 + l15][kcol];
#pragma unroll
            for (int jt = 0; jt < 4; jt++) {
                short8 bfr = *(const short8*)&Kp[jt * 16 + l15][kcol];
                s[jt] = MFMA16(af, bfr, s[jt]);
            }
        }

        // ---- fixed-max softmax: P = exp(S), accumulate row sums ----
#pragma unroll
        for (int jt = 0; jt < 4; jt++)
#pragma unroll
            for (int r = 0; r < 4; r++) {
                float p = __expf(s[jt][r]);
                lp[r] += p;
                Ps[wv * 16 + quad * 4 + r][jt * 16 + l15] = f2bf(p);
            }
        // Ps is wave-local: no barrier needed before PV.

        // ---- O += P[16x64] . V[64x64] ----
#pragma unroll
        for (int ks = 0; ks < 2; ks++) {
            const int kcol = ks * 32 + quad * 8;
            short8 af = *(const short8*)&Ps[wv * 16 + l15][kcol];
#pragma unroll
            for (int nt = 0; nt < 4; nt++) {
                short8 bfr = *(const short8*)&Vt[nt * 16 + l15][kcol];
                oacc[nt] = MFMA16(af, bfr, oacc[nt]);
            }
        }
    }

    // ---- reduce l across the 16 column-lanes, write O/l ----
#pragma unroll
    for (int r = 0; r < 4; r++) {
#pragma unroll
        for (int off = 1; off < 16; off <<= 1) lp[r] += __shfl_xor(lp[r], off);
        const float inv = 1.0f / lp[r];
        const int row = q0 + wv * 16 + quad * 4 + r;
#pragma unroll
        for (int nt = 0; nt < 4; nt++)
            outp[(size_t)row * 1024 + h * 64 + nt * 16 + l15] = f2bf(oacc[nt][r] * inv);
    }
}

// ---------------------------------------------------------------------------
extern "C" void kernel_launch(void* const* d_in, const int* in_sizes, int n_in,
                              void* d_out, int out_size, void* d_ws, size_t ws_size,
                              hipStream_t stream)
{
    const float* x  = (const float*)d_in[0];
    const float* wq = (const float*)d_in[1];
    const float* wk = (const float*)d_in[2];
    const float* wv = (const float*)d_in[3];
    const float* wo = (const float*)d_in[4];
    const float* cw = (const float*)d_in[5];
    const float* er = (const float*)d_in[6];
    float* out = (float*)d_out;
    unsigned short* ws = (unsigned short*)d_ws;

    // 4 regions x 2M shorts = 16 MiB total (proven budget).
    const size_t SZ = (size_t)2048 * 1024;
    unsigned short* A0 = ws;            // q_raw -> kc       -> (woT after attn)
    unsigned short* A1 = ws + SZ;       // k_raw -> vT
    unsigned short* A2 = ws + 2 * SZ;   // v_raw -> attn_out
    unsigned short* A3 = ws + 3 * SZ;   // qc

    // Fused QKV GEMM: [q|k|v] = x @ [wq|wk|wv], in-kernel B transpose staging.
    gemm128<true, false, false><<<dim3(24, 16), 256, 0, stream>>>(
        x, wq, wk, wv, A0, A1, A2, 2048, 1024, 1024);
    conv_qk<<<1024, 256, 0, stream>>>(A0, cw, A3);              // qc
    conv_qk<<<1024, 256, 0, stream>>>(A1, cw, A0);              // kc
    conv_vt<<<dim3(32, 16), 256, 0, stream>>>(A2, cw, A1);      // vT [h*64+d][w]
    attn16<<<dim3(32, 16), 256, 0, stream>>>(A3, A0, A1, er, A2);
    wtrans<<<dim3(16, 16), 256, 0, stream>>>(wo, A0, 1024, 1024);   // woT (kc dead)
    gemm128<false, true, true><<<dim3(8, 16), 256, 0, stream>>>(
        A2, A0, A0, A0, out, out, out, 2048, 1024, 1024);
}

// Round 5
// 214.505 us; speedup vs baseline: 1.3921x; 1.0586x over previous
//
#include <hip/hip_runtime.h>
#include <hip/hip_bf16.h>

typedef __attribute__((ext_vector_type(8))) short short8;
typedef __attribute__((ext_vector_type(4))) float floatx4;

__device__ __forceinline__ float bf2f(unsigned short b) {
    union { unsigned int u; float f; } v; v.u = ((unsigned int)b) << 16; return v.f;
}
__device__ __forceinline__ unsigned short f2bf(float f) {
    union { float f; unsigned int u; } v; v.f = f;
    unsigned int r = v.u + 0x7fffu + ((v.u >> 16) & 1u);   // RNE
    return (unsigned short)(r >> 16);
}
__device__ __forceinline__ unsigned int pk2bf(float a, float b) {
    __hip_bfloat162 h = __float22bfloat162_rn(make_float2(a, b));
    union { __hip_bfloat162 h; unsigned int u; } v; v.h = h; return v.u;
}

union Pack16 { uint4 v[2]; unsigned short u[16]; };
// load 16 contiguous f32, scale, convert to bf16
__device__ __forceinline__ void cvt16(const float* __restrict__ src, float s, Pack16& t) {
    float tmp[16];
    *(float4*)&tmp[0]  = ((const float4*)src)[0];
    *(float4*)&tmp[4]  = ((const float4*)src)[1];
    *(float4*)&tmp[8]  = ((const float4*)src)[2];
    *(float4*)&tmp[12] = ((const float4*)src)[3];
#pragma unroll
    for (int i = 0; i < 16; i++) t.u[i] = f2bf(tmp[i] * s);
}

#define MFMA16(a, b, c) __builtin_amdgcn_mfma_f32_16x16x32_bf16((a), (b), (c), 0, 0, 0)

// ---------------------------------------------------------------------------
// 128x128-tile GEMM, BK=64, 4 waves in 2x2, each wave 4x4 MFMA 16x16 tiles.
// (unchanged from round 4 — passed, not the focus this round)
// ---------------------------------------------------------------------------
template<bool A_F32, bool BT_PRE, bool C_F32>
__global__ __launch_bounds__(256) void gemm128(
    const void* __restrict__ Ap,
    const void* __restrict__ B0, const void* __restrict__ B1, const void* __restrict__ B2,
    void* __restrict__ C0, void* __restrict__ C1, void* __restrict__ C2,
    int M, int N, int K)
{
    __shared__ __align__(16) unsigned short As[128][72];   // [m][k]
    __shared__ __align__(16) unsigned short Bs[128][72];   // [n][k]
    const int tid = threadIdx.x;
    const int sel = blockIdx.x >> 3;
    const int n0  = (blockIdx.x & 7) * 128;
    const int m0  = blockIdx.y * 128;
    const void* Bp = (sel == 0) ? B0 : (sel == 1) ? B1 : B2;
    void*       Cp = (sel == 0) ? C0 : (sel == 1) ? C1 : C2;

    const int wv = tid >> 6, lane = tid & 63;
    const int quad = lane >> 4, l15 = lane & 15;
    const int wm0 = (wv >> 1) * 64, wn0 = (wv & 1) * 64;

    floatx4 acc[4][4] = {};

    for (int k0 = 0; k0 < K; k0 += 64) {
        __syncthreads();
        {
            const int r = tid >> 2, c = (tid & 3) * 16;
#pragma unroll
            for (int p = 0; p < 2; p++) {
                const int row = p * 64 + r;
                if (A_F32) {
                    Pack16 t;
                    cvt16((const float*)Ap + (size_t)(m0 + row) * K + k0 + c, 1.0f, t);
                    *(uint4*)&As[row][c]     = t.v[0];
                    *(uint4*)&As[row][c + 8] = t.v[1];
                } else {
                    const uint4* a = (const uint4*)((const unsigned short*)Ap +
                                                    (size_t)(m0 + row) * K + k0 + c);
                    uint4 x0 = a[0], x1 = a[1];
                    *(uint4*)&As[row][c]     = x0;
                    *(uint4*)&As[row][c + 8] = x1;
                }
            }
        }
        if (BT_PRE) {
            const int r = tid >> 2, c = (tid & 3) * 16;
#pragma unroll
            for (int p = 0; p < 2; p++) {
                const int row = p * 64 + r;
                const uint4* b = (const uint4*)((const unsigned short*)Bp +
                                                (size_t)(n0 + row) * K + k0 + c);
                uint4 x0 = b[0], x1 = b[1];
                *(uint4*)&Bs[row][c]     = x0;
                *(uint4*)&Bs[row][c + 8] = x1;
            }
        } else {
            const int kr = tid >> 2, nb = (tid & 3) * 32;
            float t[32];
            const float* b = (const float*)Bp + (size_t)(k0 + kr) * N + n0 + nb;
#pragma unroll
            for (int i = 0; i < 8; i++) *(float4*)&t[i * 4] = ((const float4*)b)[i];
            const int col = ((kr >> 3) ^ ((nb >> 5) & 3)) * 8 + (kr & 7);
#pragma unroll
            for (int j = 0; j < 32; j++) Bs[nb + j][col] = f2bf(t[j]);
        }
        __syncthreads();

#pragma unroll
        for (int ks = 0; ks < 2; ks++) {
            const int kc = ks * 32 + quad * 8;
            short8 af[4], bfr[4];
#pragma unroll
            for (int i = 0; i < 4; i++)
                af[i] = *(const short8*)&As[wm0 + i * 16 + l15][kc];
#pragma unroll
            for (int i = 0; i < 4; i++) {
                int bcol;
                if (BT_PRE) bcol = kc;
                else {
                    const int cx = ((wn0 + i * 16) >> 5) & 3;
                    bcol = ((ks * 4 + quad) ^ cx) * 8;
                }
                bfr[i] = *(const short8*)&Bs[wn0 + i * 16 + l15][bcol];
            }
#pragma unroll
            for (int mt = 0; mt < 4; mt++)
#pragma unroll
                for (int nt = 0; nt < 4; nt++)
                    acc[mt][nt] = MFMA16(af[mt], bfr[nt], acc[mt][nt]);
        }
    }

#pragma unroll
    for (int mt = 0; mt < 4; mt++)
#pragma unroll
        for (int nt = 0; nt < 4; nt++)
#pragma unroll
            for (int r = 0; r < 4; r++) {
                const int row = m0 + wm0 + mt * 16 + quad * 4 + r;
                const int col = n0 + wn0 + nt * 16 + l15;
                if (C_F32)
                    ((float*)Cp)[(size_t)row * N + col] = acc[mt][nt][r];
                else
                    ((unsigned short*)Cp)[(size_t)row * N + col] = f2bf(acc[mt][nt][r]);
            }
}

// ---------------------------------------------------------------------------
// Weight transpose: W f32 [K][N] -> WT bf16 [N][K]. (unchanged)
// ---------------------------------------------------------------------------
__global__ __launch_bounds__(256) void wtrans(
    const float* __restrict__ W, unsigned short* __restrict__ WT, int Kd, int Nd)
{
    __shared__ __align__(16) unsigned short T[64][72];
    const int tid = threadIdx.x;
    const int n0 = blockIdx.x * 64, k0 = blockIdx.y * 64;
    {
        const int kr = tid >> 2, nc = (tid & 3) * 16;
        Pack16 t;
        cvt16(W + (size_t)(k0 + kr) * Nd + n0 + nc, 1.0f, t);
#pragma unroll
        for (int j = 0; j < 16; j++) T[nc + j][kr] = t.u[j];
    }
    __syncthreads();
    {
        const int nr = tid >> 2, kc = (tid & 3) * 16;
        uint4 x0 = *(const uint4*)&T[nr][kc];
        uint4 x1 = *(const uint4*)&T[nr][kc + 8];
        uint4* dst = (uint4*)(WT + (size_t)(n0 + nr) * Kd + k0 + kc);
        dst[0] = x0; dst[1] = x1;
    }
}

// ---------------------------------------------------------------------------
// Depthwise conv k=3 same-pad along w, layout-preserving. (unchanged)
// ---------------------------------------------------------------------------
__global__ __launch_bounds__(256) void conv_qk(
    const unsigned short* __restrict__ in, const float* __restrict__ cw,
    unsigned short* __restrict__ out)
{
    const int idx = blockIdx.x * 256 + threadIdx.x;   // [0, 2048*128)
    const int w = idx >> 7, c0 = (idx & 127) * 8;
    union { uint4 v; unsigned short u[8]; } a = {}, b, c = {};
    b.v = *(const uint4*)(in + (size_t)w * 1024 + c0);
    if (w > 0)    a.v = *(const uint4*)(in + (size_t)(w - 1) * 1024 + c0);
    if (w < 2047) c.v = *(const uint4*)(in + (size_t)(w + 1) * 1024 + c0);
    union { uint4 v; unsigned short u[8]; } o;
#pragma unroll
    for (int i = 0; i < 8; i++) {
        const float* k3 = cw + (size_t)(c0 + i) * 3;
        o.u[i] = f2bf(bf2f(a.u[i]) * k3[0] + bf2f(b.u[i]) * k3[1] + bf2f(c.u[i]) * k3[2]);
    }
    *(uint4*)(out + (size_t)w * 1024 + c0) = o.v;
}

// ---------------------------------------------------------------------------
// Depthwise conv + per-head transpose: v_raw [w][c] -> vT [h*64+d][w]. (unchanged)
// ---------------------------------------------------------------------------
__global__ __launch_bounds__(256) void conv_vt(
    const unsigned short* __restrict__ in, const float* __restrict__ cw,
    unsigned short* __restrict__ vT)
{
    __shared__ __align__(16) unsigned short T[64][72];
    const int tid = threadIdx.x;
    const int w0 = blockIdx.x * 64, h = blockIdx.y;
    {
        const int wr = tid >> 2, c4 = (tid & 3) * 16;
        const int cg = h * 64 + c4;
        const int w = w0 + wr;
        union { uint4 v[2]; unsigned short u[16]; } a = {}, b, c = {};
        b.v[0] = *(const uint4*)(in + (size_t)w * 1024 + cg);
        b.v[1] = *(const uint4*)(in + (size_t)w * 1024 + cg + 8);
        if (w > 0) {
            a.v[0] = *(const uint4*)(in + (size_t)(w - 1) * 1024 + cg);
            a.v[1] = *(const uint4*)(in + (size_t)(w - 1) * 1024 + cg + 8);
        }
        if (w < 2047) {
            c.v[0] = *(const uint4*)(in + (size_t)(w + 1) * 1024 + cg);
            c.v[1] = *(const uint4*)(in + (size_t)(w + 1) * 1024 + cg + 8);
        }
#pragma unroll
        for (int i = 0; i < 16; i++) {
            const float* k3 = cw + (size_t)(cg + i) * 3;
            T[c4 + i][wr] = f2bf(bf2f(a.u[i]) * k3[0] + bf2f(b.u[i]) * k3[1] +
                                 bf2f(c.u[i]) * k3[2]);
        }
    }
    __syncthreads();
    {
        const int dr = tid >> 2, w4 = (tid & 3) * 16;
        uint4 x0 = *(const uint4*)&T[dr][w4];
        uint4 x1 = *(const uint4*)&T[dr][w4 + 8];
        uint4* dst = (uint4*)(vT + (size_t)(h * 64 + dr) * 2048 + w0 + w4);
        dst[0] = x0; dst[1] = x1;
    }
}

// ---------------------------------------------------------------------------
// Fused attention, wave-per-key-tile design.
//   Q'[i] = [q_i | er[:,i]] * (sc*log2e)      K'[j] = [k_j | q_j]
//   Wave wv processes kt = 4*i+wv (8 tiles): full 64x64 S^T = K'.Q'^T via
//   MFMA (A=K' direct-global frags, B=Q' frags preloaded in regs), P=exp2(S),
//   P -> LDS (b64 packed, wave-local), O += P.V (V frags direct-global from
//   vT). No barriers in the loop. Final cross-wave combine of O,l via LDS.
// ---------------------------------------------------------------------------
__global__ __launch_bounds__(256, 2) void attn16(
    const unsigned short* __restrict__ qc, const unsigned short* __restrict__ kc,
    const unsigned short* __restrict__ vT, const float* __restrict__ er,
    unsigned short* __restrict__ outp)
{
    // phase A: Qp[64][136] (17408 B) + Ps[4][64][72] (4*9216 B) = 54272 B
    // phase B: Of[4][65][68] f32 = 70720 B   (union)
    __shared__ __align__(16) unsigned char smem[70720];
    unsigned short* Qp = (unsigned short*)smem;

    const int tid = threadIdx.x;
    const int q0 = blockIdx.x * 64, h = blockIdx.y;
    const int wv = tid >> 6, lane = tid & 63;
    const int quad = lane >> 4, l15 = lane & 15;
    const float sc2 = 0.03125f * 1.44269504f;   // 1/sqrt(1024) * log2(e)

    // ---- stage Q' (once), pre-scaled for exp2 ----
    {
        const int m = tid >> 2, c4 = (tid & 3) * 16;
        union { uint4 v[2]; unsigned short u[16]; } t;
        t.v[0] = *(const uint4*)(qc + (size_t)(q0 + m) * 1024 + h * 64 + c4);
        t.v[1] = *(const uint4*)(qc + (size_t)(q0 + m) * 1024 + h * 64 + c4 + 8);
#pragma unroll
        for (int i = 0; i < 16; i++) t.u[i] = f2bf(bf2f(t.u[i]) * sc2);
        *(uint4*)&Qp[m * 136 + c4]     = t.v[0];
        *(uint4*)&Qp[m * 136 + c4 + 8] = t.v[1];
        Pack16 e;
        cvt16(er + (size_t)m * 2048 + q0 + c4, sc2, e);   // m plays d
#pragma unroll
        for (int j = 0; j < 16; j++) Qp[(c4 + j) * 136 + 64 + m] = e.u[j];
    }
    __syncthreads();

    // ---- preload Q' B-fragments (held in regs for all 32 kt tiles) ----
    short8 Bq[4][4];
#pragma unroll
    for (int qm = 0; qm < 4; qm++)
#pragma unroll
        for (int ks = 0; ks < 4; ks++)
            Bq[qm][ks] = *(const short8*)&Qp[(qm * 16 + l15) * 136 + ks * 32 + quad * 8];

    unsigned short* Ps = (unsigned short*)(smem + 17408 + wv * 9216);  // [64][72]

    floatx4 oacc[4][4] = {};
    float lp[4] = {0.f, 0.f, 0.f, 0.f};

    for (int i = 0; i < 8; i++) {
        const int kt = 4 * i + wv;
        // ---- S^T = K' . Q'^T : A-frags direct from global ----
        floatx4 s[4][4] = {};
#pragma unroll
        for (int half = 0; half < 2; half++) {
            short8 Af[2][4];
#pragma unroll
            for (int kmh = 0; kmh < 2; kmh++)
#pragma unroll
                for (int ks = 0; ks < 4; ks++) {
                    const int row = kt * 64 + (half * 2 + kmh) * 16 + l15;
                    const unsigned short* src = (ks < 2) ? kc : qc;
                    const int col = h * 64 + (ks & 1) * 32 + quad * 8;
                    Af[kmh][ks] = *(const short8*)(src + (size_t)row * 1024 + col);
                }
#pragma unroll
            for (int ks = 0; ks < 4; ks++)
#pragma unroll
                for (int kmh = 0; kmh < 2; kmh++)
#pragma unroll
                    for (int qm = 0; qm < 4; qm++)
                        s[half * 2 + kmh][qm] =
                            MFMA16(Af[kmh][ks], Bq[qm][ks], s[half * 2 + kmh][qm]);
        }

        // ---- P = exp2(S^T), packed b64 writes to Ps[q][key], row sums ----
#pragma unroll
        for (int km = 0; km < 4; km++)
#pragma unroll
            for (int qm = 0; qm < 4; qm++) {
                float p0 = exp2f(s[km][qm][0]);
                float p1 = exp2f(s[km][qm][1]);
                float p2 = exp2f(s[km][qm][2]);
                float p3 = exp2f(s[km][qm][3]);
                lp[qm] += (p0 + p1) + (p2 + p3);
                uint2 w;
                w.x = pk2bf(p0, p1);
                w.y = pk2bf(p2, p3);
                *(uint2*)&Ps[(qm * 16 + l15) * 72 + km * 16 + quad * 4] = w;
            }

        // ---- O += P . V : P from LDS (wave-local), V direct from vT ----
#pragma unroll
        for (int ks = 0; ks < 2; ks++) {
            short8 Pa[4], Vb[4];
#pragma unroll
            for (int mt = 0; mt < 4; mt++)
                Pa[mt] = *(const short8*)&Ps[(mt * 16 + l15) * 72 + ks * 32 + quad * 8];
#pragma unroll
            for (int nt = 0; nt < 4; nt++)
                Vb[nt] = *(const short8*)(vT + (size_t)(h * 64 + nt * 16 + l15) * 2048 +
                                          kt * 64 + ks * 32 + quad * 8);
#pragma unroll
            for (int mt = 0; mt < 4; mt++)
#pragma unroll
                for (int nt = 0; nt < 4; nt++)
                    oacc[mt][nt] = MFMA16(Pa[mt], Vb[nt], oacc[mt][nt]);
        }
    }

    // ---- cross-wave combine: O (f32) and l via LDS ----
#pragma unroll
    for (int qm = 0; qm < 4; qm++) {
        lp[qm] += __shfl_xor(lp[qm], 16);
        lp[qm] += __shfl_xor(lp[qm], 32);
    }
    __syncthreads();   // all waves done with Qp/Ps reads
    float* OfW = (float*)smem + wv * 4420;   // [65][68]: rows 0..63 = O^T[d][q], row 64 = l[q]
#pragma unroll
    for (int mt = 0; mt < 4; mt++)
#pragma unroll
        for (int nt = 0; nt < 4; nt++) {
            floatx4 o = oacc[mt][nt];
            *(float4*)&OfW[(nt * 16 + l15) * 68 + mt * 16 + quad * 4] =
                make_float4(o[0], o[1], o[2], o[3]);
        }
    if (quad == 0) {
#pragma unroll
        for (int qm = 0; qm < 4; qm++) OfW[64 * 68 + qm * 16 + l15] = lp[qm];
    }
    __syncthreads();

    // ---- reduce 4 partials, divide, store. wave wv owns d rows [wv*16, +16) --
    {
        const int d = wv * 16 + l15;
#pragma unroll
        for (int i4 = 0; i4 < 4; i4++) {
            float4 os = make_float4(0.f, 0.f, 0.f, 0.f);
            float4 ls = make_float4(0.f, 0.f, 0.f, 0.f);
#pragma unroll
            for (int s4 = 0; s4 < 4; s4++) {
                const float* R = (const float*)smem + s4 * 4420;
                float4 t  = *(const float4*)&R[d * 68 + quad * 16 + i4 * 4];
                float4 tl = *(const float4*)&R[64 * 68 + quad * 16 + i4 * 4];
                os.x += t.x;  os.y += t.y;  os.z += t.z;  os.w += t.w;
                ls.x += tl.x; ls.y += tl.y; ls.z += tl.z; ls.w += tl.w;
            }
            const int qb4 = quad * 16 + i4 * 4;
            const size_t colb = (size_t)h * 64 + d;
            outp[(size_t)(q0 + qb4 + 0) * 1024 + colb] = f2bf(os.x / ls.x);
            outp[(size_t)(q0 + qb4 + 1) * 1024 + colb] = f2bf(os.y / ls.y);
            outp[(size_t)(q0 + qb4 + 2) * 1024 + colb] = f2bf(os.z / ls.z);
            outp[(size_t)(q0 + qb4 + 3) * 1024 + colb] = f2bf(os.w / ls.w);
        }
    }
}

// ---------------------------------------------------------------------------
extern "C" void kernel_launch(void* const* d_in, const int* in_sizes, int n_in,
                              void* d_out, int out_size, void* d_ws, size_t ws_size,
                              hipStream_t stream)
{
    const float* x  = (const float*)d_in[0];
    const float* wq = (const float*)d_in[1];
    const float* wk = (const float*)d_in[2];
    const float* wv = (const float*)d_in[3];
    const float* wo = (const float*)d_in[4];
    const float* cw = (const float*)d_in[5];
    const float* er = (const float*)d_in[6];
    float* out = (float*)d_out;
    unsigned short* ws = (unsigned short*)d_ws;

    // 4 regions x 2M shorts = 16 MiB total (proven budget).
    const size_t SZ = (size_t)2048 * 1024;
    unsigned short* A0 = ws;            // q_raw -> kc       -> (woT after attn)
    unsigned short* A1 = ws + SZ;       // k_raw -> vT
    unsigned short* A2 = ws + 2 * SZ;   // v_raw -> attn_out
    unsigned short* A3 = ws + 3 * SZ;   // qc

    gemm128<true, false, false><<<dim3(24, 16), 256, 0, stream>>>(
        x, wq, wk, wv, A0, A1, A2, 2048, 1024, 1024);
    conv_qk<<<1024, 256, 0, stream>>>(A0, cw, A3);              // qc
    conv_qk<<<1024, 256, 0, stream>>>(A1, cw, A0);              // kc
    conv_vt<<<dim3(32, 16), 256, 0, stream>>>(A2, cw, A1);      // vT [h*64+d][w]
    attn16<<<dim3(32, 16), 256, 0, stream>>>(A3, A0, A1, er, A2);
    wtrans<<<dim3(16, 16), 256, 0, stream>>>(wo, A0, 1024, 1024);   // woT
    gemm128<false, true, true><<<dim3(8, 16), 256, 0, stream>>>(
        A2, A0, A0, A0, out, out, out, 2048, 1024, 1024);
}

// Round 6
// 199.177 us; speedup vs baseline: 1.4992x; 1.0770x over previous
//
#include <hip/hip_runtime.h>
#include <hip/hip_bf16.h>

typedef __attribute__((ext_vector_type(8))) short short8;
typedef __attribute__((ext_vector_type(4))) float floatx4;

__device__ __forceinline__ float bf2f(unsigned short b) {
    union { unsigned int u; float f; } v; v.u = ((unsigned int)b) << 16; return v.f;
}
__device__ __forceinline__ unsigned short f2bf(float f) {
    union { float f; unsigned int u; } v; v.f = f;
    unsigned int r = v.u + 0x7fffu + ((v.u >> 16) & 1u);   // RNE
    return (unsigned short)(r >> 16);
}
__device__ __forceinline__ unsigned int pk2bf(float a, float b) {
    __hip_bfloat162 h = __float22bfloat162_rn(make_float2(a, b));
    union { __hip_bfloat162 h; unsigned int u; } v; v.h = h; return v.u;
}

union Pack16 { uint4 v[2]; unsigned short u[16]; };
// load 16 contiguous f32, scale, convert to bf16
__device__ __forceinline__ void cvt16(const float* __restrict__ src, float s, Pack16& t) {
    float tmp[16];
    *(float4*)&tmp[0]  = ((const float4*)src)[0];
    *(float4*)&tmp[4]  = ((const float4*)src)[1];
    *(float4*)&tmp[8]  = ((const float4*)src)[2];
    *(float4*)&tmp[12] = ((const float4*)src)[3];
#pragma unroll
    for (int i = 0; i < 16; i++) t.u[i] = f2bf(tmp[i] * s);
}

#define MFMA16(a, b, c) __builtin_amdgcn_mfma_f32_16x16x32_bf16((a), (b), (c), 0, 0, 0)

// ---------------------------------------------------------------------------
// x f32 [2048][1024] -> bf16 same layout (one-time; makes GEMM A-staging
// pure copies and deletes per-k-step converts from the QKV hot loop).
// ---------------------------------------------------------------------------
__global__ __launch_bounds__(256) void xcvt(
    const float* __restrict__ x, unsigned short* __restrict__ xb)
{
    const size_t i = ((size_t)blockIdx.x * 256 + threadIdx.x) * 8;
    float4 a = *(const float4*)(x + i), b = *(const float4*)(x + i + 4);
    union { uint4 v; unsigned short u[8]; } o;
    o.u[0] = f2bf(a.x); o.u[1] = f2bf(a.y); o.u[2] = f2bf(a.z); o.u[3] = f2bf(a.w);
    o.u[4] = f2bf(b.x); o.u[5] = f2bf(b.y); o.u[6] = f2bf(b.z); o.u[7] = f2bf(b.w);
    *(uint4*)(xb + i) = o.v;
}

// ---------------------------------------------------------------------------
// 128(M)x64(N)-tile GEMM, BK=64. 4 waves in 2(m)x2(n), each wave 4x2 MFMA
// 16x16 tiles. A always bf16 row-major [M][K] (straight-copy staging).
// B: BT_PRE ? bf16 pre-transposed [N][K] (straight copy)
//           : f32 row-major [K][N], transpose-staged with XOR chunk swizzle.
// Fused over up to 3 (B,C): sel = blockIdx.x>>4, n0 = (blockIdx.x&15)*64.
// Grid QKV: (48,16) -> 768 blocks (3/CU); final: (16,16) -> 256 blocks.
// ---------------------------------------------------------------------------
template<bool BT_PRE, bool C_F32>
__global__ __launch_bounds__(256) void gemmMN(
    const unsigned short* __restrict__ Abf,
    const void* __restrict__ B0, const void* __restrict__ B1, const void* __restrict__ B2,
    void* __restrict__ C0, void* __restrict__ C1, void* __restrict__ C2,
    int M, int N, int K)
{
    __shared__ __align__(16) unsigned short As[128][72];   // [m][k]
    __shared__ __align__(16) unsigned short Bs[64][72];    // [n][k]
    const int tid = threadIdx.x;
    const int sel = blockIdx.x >> 4;
    const int n0  = (blockIdx.x & 15) * 64;
    const int m0  = blockIdx.y * 128;
    const void* Bp = (sel == 0) ? B0 : (sel == 1) ? B1 : B2;
    void*       Cp = (sel == 0) ? C0 : (sel == 1) ? C1 : C2;

    const int wv = tid >> 6, lane = tid & 63;
    const int quad = lane >> 4, l15 = lane & 15;
    const int wm0 = (wv >> 1) * 64, wn0 = (wv & 1) * 32;

    floatx4 acc[4][2] = {};

    for (int k0 = 0; k0 < K; k0 += 64) {
        __syncthreads();
        // ---- stage A: 128x64 bf16 straight copy ----
        {
            const int r = tid >> 2, c = (tid & 3) * 16;
#pragma unroll
            for (int p = 0; p < 2; p++) {
                const int row = p * 64 + r;
                const uint4* a = (const uint4*)(Abf + (size_t)(m0 + row) * K + k0 + c);
                uint4 x0 = a[0], x1 = a[1];
                *(uint4*)&As[row][c]     = x0;
                *(uint4*)&As[row][c + 8] = x1;
            }
        }
        // ---- stage B: 64(k)x64(n) ----
        if (BT_PRE) {
            const int r = tid >> 2, c = (tid & 3) * 16;
            const uint4* b = (const uint4*)((const unsigned short*)Bp +
                                            (size_t)(n0 + r) * K + k0 + c);
            uint4 x0 = b[0], x1 = b[1];
            *(uint4*)&Bs[r][c]     = x0;
            *(uint4*)&Bs[r][c + 8] = x1;
        } else {
            // f32 [k][n] -> Bs[n][ ((k/8)^((n>>5)&1))*8 + k%8 ]
            const int kr = tid >> 2, nb = (tid & 3) * 16;
            float t[16];
            const float* b = (const float*)Bp + (size_t)(k0 + kr) * N + n0 + nb;
#pragma unroll
            for (int i = 0; i < 4; i++) *(float4*)&t[i * 4] = ((const float4*)b)[i];
            const int cx = (nb >> 5) & 1;   // constant over j (nb multiple of 16)
            const int colb = ((kr >> 3) ^ cx) * 8 + (kr & 7);
#pragma unroll
            for (int j = 0; j < 16; j++) Bs[nb + j][colb] = f2bf(t[j]);
        }
        __syncthreads();

#pragma unroll
        for (int ks = 0; ks < 2; ks++) {
            const int kc = ks * 32 + quad * 8;
            short8 af[4], bfr[2];
#pragma unroll
            for (int i = 0; i < 4; i++)
                af[i] = *(const short8*)&As[wm0 + i * 16 + l15][kc];
#pragma unroll
            for (int i = 0; i < 2; i++) {
                int bcol;
                if (BT_PRE) bcol = kc;
                else {
                    const int cx = ((wn0 + i * 16) >> 5) & 1;
                    bcol = ((ks * 4 + quad) ^ cx) * 8;
                }
                bfr[i] = *(const short8*)&Bs[wn0 + i * 16 + l15][bcol];
            }
#pragma unroll
            for (int mt = 0; mt < 4; mt++)
#pragma unroll
                for (int nt = 0; nt < 2; nt++)
                    acc[mt][nt] = MFMA16(af[mt], bfr[nt], acc[mt][nt]);
        }
    }

#pragma unroll
    for (int mt = 0; mt < 4; mt++)
#pragma unroll
        for (int nt = 0; nt < 2; nt++)
#pragma unroll
            for (int r = 0; r < 4; r++) {
                const int row = m0 + wm0 + mt * 16 + quad * 4 + r;
                const int col = n0 + wn0 + nt * 16 + l15;
                if (C_F32)
                    ((float*)Cp)[(size_t)row * N + col] = acc[mt][nt][r];
                else
                    ((unsigned short*)Cp)[(size_t)row * N + col] = f2bf(acc[mt][nt][r]);
            }
}

// ---------------------------------------------------------------------------
// Weight transpose: W f32 [K][N] -> WT bf16 [N][K]. (unchanged)
// ---------------------------------------------------------------------------
__global__ __launch_bounds__(256) void wtrans(
    const float* __restrict__ W, unsigned short* __restrict__ WT, int Kd, int Nd)
{
    __shared__ __align__(16) unsigned short T[64][72];
    const int tid = threadIdx.x;
    const int n0 = blockIdx.x * 64, k0 = blockIdx.y * 64;
    {
        const int kr = tid >> 2, nc = (tid & 3) * 16;
        Pack16 t;
        cvt16(W + (size_t)(k0 + kr) * Nd + n0 + nc, 1.0f, t);
#pragma unroll
        for (int j = 0; j < 16; j++) T[nc + j][kr] = t.u[j];
    }
    __syncthreads();
    {
        const int nr = tid >> 2, kc = (tid & 3) * 16;
        uint4 x0 = *(const uint4*)&T[nr][kc];
        uint4 x1 = *(const uint4*)&T[nr][kc + 8];
        uint4* dst = (uint4*)(WT + (size_t)(n0 + nr) * Kd + k0 + kc);
        dst[0] = x0; dst[1] = x1;
    }
}

// ---------------------------------------------------------------------------
// Depthwise conv k=3 same-pad along w, layout-preserving. (unchanged)
// ---------------------------------------------------------------------------
__global__ __launch_bounds__(256) void conv_qk(
    const unsigned short* __restrict__ in, const float* __restrict__ cw,
    unsigned short* __restrict__ out)
{
    const int idx = blockIdx.x * 256 + threadIdx.x;   // [0, 2048*128)
    const int w = idx >> 7, c0 = (idx & 127) * 8;
    union { uint4 v; unsigned short u[8]; } a = {}, b, c = {};
    b.v = *(const uint4*)(in + (size_t)w * 1024 + c0);
    if (w > 0)    a.v = *(const uint4*)(in + (size_t)(w - 1) * 1024 + c0);
    if (w < 2047) c.v = *(const uint4*)(in + (size_t)(w + 1) * 1024 + c0);
    union { uint4 v; unsigned short u[8]; } o;
#pragma unroll
    for (int i = 0; i < 8; i++) {
        const float* k3 = cw + (size_t)(c0 + i) * 3;
        o.u[i] = f2bf(bf2f(a.u[i]) * k3[0] + bf2f(b.u[i]) * k3[1] + bf2f(c.u[i]) * k3[2]);
    }
    *(uint4*)(out + (size_t)w * 1024 + c0) = o.v;
}

// ---------------------------------------------------------------------------
// Depthwise conv + per-head transpose: v_raw [w][c] -> vT [h*64+d][w]. (unchanged)
// ---------------------------------------------------------------------------
__global__ __launch_bounds__(256) void conv_vt(
    const unsigned short* __restrict__ in, const float* __restrict__ cw,
    unsigned short* __restrict__ vT)
{
    __shared__ __align__(16) unsigned short T[64][72];
    const int tid = threadIdx.x;
    const int w0 = blockIdx.x * 64, h = blockIdx.y;
    {
        const int wr = tid >> 2, c4 = (tid & 3) * 16;
        const int cg = h * 64 + c4;
        const int w = w0 + wr;
        union { uint4 v[2]; unsigned short u[16]; } a = {}, b, c = {};
        b.v[0] = *(const uint4*)(in + (size_t)w * 1024 + cg);
        b.v[1] = *(const uint4*)(in + (size_t)w * 1024 + cg + 8);
        if (w > 0) {
            a.v[0] = *(const uint4*)(in + (size_t)(w - 1) * 1024 + cg);
            a.v[1] = *(const uint4*)(in + (size_t)(w - 1) * 1024 + cg + 8);
        }
        if (w < 2047) {
            c.v[0] = *(const uint4*)(in + (size_t)(w + 1) * 1024 + cg);
            c.v[1] = *(const uint4*)(in + (size_t)(w + 1) * 1024 + cg + 8);
        }
#pragma unroll
        for (int i = 0; i < 16; i++) {
            const float* k3 = cw + (size_t)(cg + i) * 3;
            T[c4 + i][wr] = f2bf(bf2f(a.u[i]) * k3[0] + bf2f(b.u[i]) * k3[1] +
                                 bf2f(c.u[i]) * k3[2]);
        }
    }
    __syncthreads();
    {
        const int dr = tid >> 2, w4 = (tid & 3) * 16;
        uint4 x0 = *(const uint4*)&T[dr][w4];
        uint4 x1 = *(const uint4*)&T[dr][w4 + 8];
        uint4* dst = (uint4*)(vT + (size_t)(h * 64 + dr) * 2048 + w0 + w4);
        dst[0] = x0; dst[1] = x1;
    }
}

// ---------------------------------------------------------------------------
// Fused attention, wave-per-key-tile design. (unchanged from round 5)
// ---------------------------------------------------------------------------
__global__ __launch_bounds__(256, 2) void attn16(
    const unsigned short* __restrict__ qc, const unsigned short* __restrict__ kc,
    const unsigned short* __restrict__ vT, const float* __restrict__ er,
    unsigned short* __restrict__ outp)
{
    __shared__ __align__(16) unsigned char smem[70720];
    unsigned short* Qp = (unsigned short*)smem;

    const int tid = threadIdx.x;
    const int q0 = blockIdx.x * 64, h = blockIdx.y;
    const int wv = tid >> 6, lane = tid & 63;
    const int quad = lane >> 4, l15 = lane & 15;
    const float sc2 = 0.03125f * 1.44269504f;   // 1/sqrt(1024) * log2(e)

    {
        const int m = tid >> 2, c4 = (tid & 3) * 16;
        union { uint4 v[2]; unsigned short u[16]; } t;
        t.v[0] = *(const uint4*)(qc + (size_t)(q0 + m) * 1024 + h * 64 + c4);
        t.v[1] = *(const uint4*)(qc + (size_t)(q0 + m) * 1024 + h * 64 + c4 + 8);
#pragma unroll
        for (int i = 0; i < 16; i++) t.u[i] = f2bf(bf2f(t.u[i]) * sc2);
        *(uint4*)&Qp[m * 136 + c4]     = t.v[0];
        *(uint4*)&Qp[m * 136 + c4 + 8] = t.v[1];
        Pack16 e;
        cvt16(er + (size_t)m * 2048 + q0 + c4, sc2, e);
#pragma unroll
        for (int j = 0; j < 16; j++) Qp[(c4 + j) * 136 + 64 + m] = e.u[j];
    }
    __syncthreads();

    short8 Bq[4][4];
#pragma unroll
    for (int qm = 0; qm < 4; qm++)
#pragma unroll
        for (int ks = 0; ks < 4; ks++)
            Bq[qm][ks] = *(const short8*)&Qp[(qm * 16 + l15) * 136 + ks * 32 + quad * 8];

    unsigned short* Ps = (unsigned short*)(smem + 17408 + wv * 9216);

    floatx4 oacc[4][4] = {};
    float lp[4] = {0.f, 0.f, 0.f, 0.f};

    for (int i = 0; i < 8; i++) {
        const int kt = 4 * i + wv;
        floatx4 s[4][4] = {};
#pragma unroll
        for (int half = 0; half < 2; half++) {
            short8 Af[2][4];
#pragma unroll
            for (int kmh = 0; kmh < 2; kmh++)
#pragma unroll
                for (int ks = 0; ks < 4; ks++) {
                    const int row = kt * 64 + (half * 2 + kmh) * 16 + l15;
                    const unsigned short* src = (ks < 2) ? kc : qc;
                    const int col = h * 64 + (ks & 1) * 32 + quad * 8;
                    Af[kmh][ks] = *(const short8*)(src + (size_t)row * 1024 + col);
                }
#pragma unroll
            for (int ks = 0; ks < 4; ks++)
#pragma unroll
                for (int kmh = 0; kmh < 2; kmh++)
#pragma unroll
                    for (int qm = 0; qm < 4; qm++)
                        s[half * 2 + kmh][qm] =
                            MFMA16(Af[kmh][ks], Bq[qm][ks], s[half * 2 + kmh][qm]);
        }

#pragma unroll
        for (int km = 0; km < 4; km++)
#pragma unroll
            for (int qm = 0; qm < 4; qm++) {
                float p0 = exp2f(s[km][qm][0]);
                float p1 = exp2f(s[km][qm][1]);
                float p2 = exp2f(s[km][qm][2]);
                float p3 = exp2f(s[km][qm][3]);
                lp[qm] += (p0 + p1) + (p2 + p3);
                uint2 w;
                w.x = pk2bf(p0, p1);
                w.y = pk2bf(p2, p3);
                *(uint2*)&Ps[(qm * 16 + l15) * 72 + km * 16 + quad * 4] = w;
            }

#pragma unroll
        for (int ks = 0; ks < 2; ks++) {
            short8 Pa[4], Vb[4];
#pragma unroll
            for (int mt = 0; mt < 4; mt++)
                Pa[mt] = *(const short8*)&Ps[(mt * 16 + l15) * 72 + ks * 32 + quad * 8];
#pragma unroll
            for (int nt = 0; nt < 4; nt++)
                Vb[nt] = *(const short8*)(vT + (size_t)(h * 64 + nt * 16 + l15) * 2048 +
                                          kt * 64 + ks * 32 + quad * 8);
#pragma unroll
            for (int mt = 0; mt < 4; mt++)
#pragma unroll
                for (int nt = 0; nt < 4; nt++)
                    oacc[mt][nt] = MFMA16(Pa[mt], Vb[nt], oacc[mt][nt]);
        }
    }

#pragma unroll
    for (int qm = 0; qm < 4; qm++) {
        lp[qm] += __shfl_xor(lp[qm], 16);
        lp[qm] += __shfl_xor(lp[qm], 32);
    }
    __syncthreads();
    float* OfW = (float*)smem + wv * 4420;
#pragma unroll
    for (int mt = 0; mt < 4; mt++)
#pragma unroll
        for (int nt = 0; nt < 4; nt++) {
            floatx4 o = oacc[mt][nt];
            *(float4*)&OfW[(nt * 16 + l15) * 68 + mt * 16 + quad * 4] =
                make_float4(o[0], o[1], o[2], o[3]);
        }
    if (quad == 0) {
#pragma unroll
        for (int qm = 0; qm < 4; qm++) OfW[64 * 68 + qm * 16 + l15] = lp[qm];
    }
    __syncthreads();

    {
        const int d = wv * 16 + l15;
#pragma unroll
        for (int i4 = 0; i4 < 4; i4++) {
            float4 os = make_float4(0.f, 0.f, 0.f, 0.f);
            float4 ls = make_float4(0.f, 0.f, 0.f, 0.f);
#pragma unroll
            for (int s4 = 0; s4 < 4; s4++) {
                const float* R = (const float*)smem + s4 * 4420;
                float4 t  = *(const float4*)&R[d * 68 + quad * 16 + i4 * 4];
                float4 tl = *(const float4*)&R[64 * 68 + quad * 16 + i4 * 4];
                os.x += t.x;  os.y += t.y;  os.z += t.z;  os.w += t.w;
                ls.x += tl.x; ls.y += tl.y; ls.z += tl.z; ls.w += tl.w;
            }
            const int qb4 = quad * 16 + i4 * 4;
            const size_t colb = (size_t)h * 64 + d;
            outp[(size_t)(q0 + qb4 + 0) * 1024 + colb] = f2bf(os.x / ls.x);
            outp[(size_t)(q0 + qb4 + 1) * 1024 + colb] = f2bf(os.y / ls.y);
            outp[(size_t)(q0 + qb4 + 2) * 1024 + colb] = f2bf(os.z / ls.z);
            outp[(size_t)(q0 + qb4 + 3) * 1024 + colb] = f2bf(os.w / ls.w);
        }
    }
}

// ---------------------------------------------------------------------------
extern "C" void kernel_launch(void* const* d_in, const int* in_sizes, int n_in,
                              void* d_out, int out_size, void* d_ws, size_t ws_size,
                              hipStream_t stream)
{
    const float* x  = (const float*)d_in[0];
    const float* wq = (const float*)d_in[1];
    const float* wk = (const float*)d_in[2];
    const float* wv = (const float*)d_in[3];
    const float* wo = (const float*)d_in[4];
    const float* cw = (const float*)d_in[5];
    const float* er = (const float*)d_in[6];
    float* out = (float*)d_out;
    unsigned short* ws = (unsigned short*)d_ws;

    // 4 regions x 2M shorts = 16 MiB total (proven budget).
    const size_t SZ = (size_t)2048 * 1024;
    unsigned short* A0 = ws;            // q_raw -> kc  -> woT
    unsigned short* A1 = ws + SZ;       // k_raw -> vT
    unsigned short* A2 = ws + 2 * SZ;   // v_raw -> attn_out
    unsigned short* A3 = ws + 3 * SZ;   // xbf   -> qc

    xcvt<<<1024, 256, 0, stream>>>(x, A3);                      // xbf
    gemmMN<false, false><<<dim3(48, 16), 256, 0, stream>>>(
        A3, wq, wk, wv, A0, A1, A2, 2048, 1024, 1024);          // q/k/v raw
    conv_qk<<<1024, 256, 0, stream>>>(A0, cw, A3);              // qc (xbf dead)
    conv_qk<<<1024, 256, 0, stream>>>(A1, cw, A0);              // kc
    conv_vt<<<dim3(32, 16), 256, 0, stream>>>(A2, cw, A1);      // vT [h*64+d][w]
    attn16<<<dim3(32, 16), 256, 0, stream>>>(A3, A0, A1, er, A2);
    wtrans<<<dim3(16, 16), 256, 0, stream>>>(wo, A0, 1024, 1024);   // woT (kc dead)
    gemmMN<true, true><<<dim3(16, 16), 256, 0, stream>>>(
        A2, A0, A0, A0, out, out, out, 2048, 1024, 1024);
}